// Round 1
// baseline (318.132 us; speedup 1.0000x reference)
//
#include <hip/hip_runtime.h>
#include <cstdint>
#include <cstddef>

typedef unsigned short u16;
typedef unsigned int u32;
typedef __attribute__((ext_vector_type(8))) short short8;
typedef __attribute__((ext_vector_type(4))) float f32x4;

#define T_SEQ 2048

// ---------- helpers ----------
__device__ __forceinline__ u16 f2bf(float x) {
  union { float f; u32 u; } v; v.f = x;
  u32 r = v.u + 0x7fffu + ((v.u >> 16) & 1u);
  return (u16)(r >> 16);
}
__device__ __forceinline__ float bf2f(u16 h) {
  union { u32 u; float f; } v; v.u = ((u32)h) << 16;
  return v.f;
}
__device__ __forceinline__ float wave_bcast_sum(float x) {
#pragma unroll
  for (int off = 32; off > 0; off >>= 1) x += __shfl_down(x, off);
  return __shfl(x, 0);
}
__device__ __forceinline__ void gl_lds16(const void* g, void* l) {
  __builtin_amdgcn_global_load_lds((const __attribute__((address_space(1))) u32*)g,
                                   (__attribute__((address_space(3))) u32*)l, 16, 0, 0);
}

// ---------- f32 -> bf16 convert (vectorized) ----------
__global__ __launch_bounds__(256) void cvt_bf16(const float* __restrict__ in,
                                                u16* __restrict__ out, int n4) {
  const int i = blockIdx.x * 256 + threadIdx.x;
  if (i >= n4) return;
  const float4 x = ((const float4*)in)[i];
  ushort4 o; o.x = f2bf(x.x); o.y = f2bf(x.y); o.z = f2bf(x.z); o.w = f2bf(x.w);
  ((ushort4*)out)[i] = o;
}

// ---------- transpose + convert: in[K][N] f32 -> out[N][K] bf16 ----------
__global__ __launch_bounds__(256) void tcvt(const float* __restrict__ in,
                                            u16* __restrict__ out, int K, int N) {
  __shared__ float tile[32][33];
  const int tx = threadIdx.x & 31;
  const int ty = threadIdx.x >> 5;
  const int k0 = blockIdx.x * 32;
  const int n0 = blockIdx.y * 32;
#pragma unroll
  for (int r = 0; r < 4; r++)
    tile[ty + r * 8][tx] = in[(size_t)(k0 + ty + r * 8) * N + n0 + tx];
  __syncthreads();
#pragma unroll
  for (int r = 0; r < 4; r++)
    out[(size_t)(n0 + ty + r * 8) * K + k0 + tx] = f2bf(tile[tx][ty + r * 8]);
}

// ---------- bf16 GEMM: C[M][N] = A[M][K] @ Bt[N][K]^T  (m97 structure) ----------
// GELU=false: write f32 C.  GELU=true: C = bf16(gelu(C + bias[col]))
template <bool GELU>
__global__ __launch_bounds__(256) void gemm_bt(const u16* __restrict__ A,
                                               const u16* __restrict__ Bt,
                                               void* __restrict__ Cout,
                                               const float* __restrict__ bias,
                                               int M, int N, int K) {
  __shared__ u16 As[128 * 32];  // [m][k] row-major, 64B rows
  __shared__ u16 Bs[128 * 32];  // [n][k] row-major
  const int tid = threadIdx.x;
  const int m0 = blockIdx.x * 128;
  const int n0 = blockIdx.y * 128;
  const int wave = tid >> 6;
  const int lane = tid & 63;
  const int qm = lane & 15;
  const int quad = lane >> 4;
  const int rw = (wave >> 1) * 64;
  const int cw = (wave & 1) * 64;

  // staging chunks: chunk c covers LDS row c>>2, cols (c&3)*8..+8  -> LDS offset c*16B
  const int r0 = tid >> 2, s0 = (tid & 3) * 8;
  const int r1 = (tid + 256) >> 2;  // (tid+256)&3 == tid&3
  const u16* Arow0 = A + (size_t)(m0 + r0) * K + s0;
  const u16* Arow1 = A + (size_t)(m0 + r1) * K + s0;
  const u16* Brow0 = Bt + (size_t)(n0 + r0) * K + s0;
  const u16* Brow1 = Bt + (size_t)(n0 + r1) * K + s0;

  f32x4 acc[4][4] = {};

  for (int kt = 0; kt < K; kt += 32) {
    gl_lds16(Arow0 + kt, &As[tid * 8]);
    gl_lds16(Arow1 + kt, &As[(tid + 256) * 8]);
    gl_lds16(Brow0 + kt, &Bs[tid * 8]);
    gl_lds16(Brow1 + kt, &Bs[(tid + 256) * 8]);
    __syncthreads();
    short8 af[4], bf[4];
#pragma unroll
    for (int i = 0; i < 4; i++)
      af[i] = *(const short8*)&As[(rw + i * 16 + qm) * 32 + quad * 8];
#pragma unroll
    for (int j = 0; j < 4; j++)
      bf[j] = *(const short8*)&Bs[(cw + j * 16 + qm) * 32 + quad * 8];
#pragma unroll
    for (int i = 0; i < 4; i++)
#pragma unroll
      for (int j = 0; j < 4; j++)
        acc[i][j] = __builtin_amdgcn_mfma_f32_16x16x32_bf16(af[i], bf[j], acc[i][j], 0, 0, 0);
    __syncthreads();
  }

#pragma unroll
  for (int i = 0; i < 4; i++) {
    const int row = m0 + rw + i * 16 + quad * 4;  // D: row = quad*4 + reg
#pragma unroll
    for (int j = 0; j < 4; j++) {
      const int col = n0 + cw + j * 16 + qm;      // D: col = lane&15
      if (GELU) {
        u16* C = (u16*)Cout;
        const float b = bias[col];
#pragma unroll
        for (int r = 0; r < 4; r++) {
          float x = acc[i][j][r] + b;
          float g = 0.5f * x * (1.0f + erff(x * 0.7071067811865475f));
          C[(size_t)(row + r) * N + col] = f2bf(g);
        }
      } else {
        float* C = (float*)Cout;
#pragma unroll
        for (int r = 0; r < 4; r++)
          C[(size_t)(row + r) * N + col] = acc[i][j][r];
      }
    }
  }
}

// ---------- in-place layernorm over 256 cols, with bias added first ----------
__global__ __launch_bounds__(256) void ln_rows(float* __restrict__ X,
                                               const float* __restrict__ bias) {
  const int row = blockIdx.x * 4 + (threadIdx.x >> 6);
  const int lane = threadIdx.x & 63;
  float4 x = *(float4*)&X[(size_t)row * 256 + lane * 4];
  const float4 b = *(const float4*)&bias[lane * 4];
  x.x += b.x; x.y += b.y; x.z += b.z; x.w += b.w;
  float s = x.x + x.y + x.z + x.w;
  float s2 = x.x * x.x + x.y * x.y + x.z * x.z + x.w * x.w;
  s = wave_bcast_sum(s);
  s2 = wave_bcast_sum(s2);
  const float mu = s * (1.0f / 256.0f);
  const float var = s2 * (1.0f / 256.0f) - mu * mu;
  const float inv = rsqrtf(var + 1e-5f);
  x.x = (x.x - mu) * inv; x.y = (x.y - mu) * inv;
  x.z = (x.z - mu) * inv; x.w = (x.w - mu) * inv;
  *(float4*)&X[(size_t)row * 256 + lane * 4] = x;
}

// ---------- fractional shift + causal window average ----------
__global__ __launch_bounds__(256) void shift_ctx(const float* __restrict__ a,
                                                 float* __restrict__ actx,
                                                 const float* __restrict__ theta) {
  const int idx = blockIdx.x * 256 + threadIdx.x;  // B*T*64 threads
  const int d4 = (idx & 63) * 4;
  const int row = idx >> 6;
  const int bb = row >> 11;          // T=2048
  const int t = row & (T_SEQ - 1);
  const float th = fminf(fmaxf(theta[0], -12.0f), 12.0f);
  const float delta = 2.0f + 4.0f * (1.0f / (1.0f + expf(-th)));
  const float dl = fminf(fmaxf(delta, 0.0f), (float)(T_SEQ - 1));
  const float nf = floorf(dl);
  const float alpha = dl - nf;
  const int ni = (int)nf;
  const float center = fminf(fmaxf((float)t + delta, 0.0f), (float)t);
  float sx = 0, sy = 0, sz = 0, sw = 0, cnt = 0.0f;
  const float* ab = a + (size_t)bb * T_SEQ * 256;
#pragma unroll
  for (int j = 0; j < 6; j++) {
    const int tau = t - 5 + j;
    if (tau < 0) continue;
    if (fabsf((float)tau - center) > 5.0f) continue;  // tau<=t holds by construction
    cnt += 1.0f;
    const int i0 = min(max(tau - ni, 0), T_SEQ - 1);
    const int i1 = min(i0 + 1, T_SEQ - 1);
    const float4 a0 = *(const float4*)&ab[(size_t)i0 * 256 + d4];
    const float4 a1 = *(const float4*)&ab[(size_t)i1 * 256 + d4];
    sx += a0.x + alpha * (a1.x - a0.x);
    sy += a0.y + alpha * (a1.y - a0.y);
    sz += a0.z + alpha * (a1.z - a0.z);
    sw += a0.w + alpha * (a1.w - a0.w);
  }
  const float sc = 1.0f / fmaxf(cnt, 1e-8f);
  float4 o; o.x = sx * sc; o.y = sy * sc; o.z = sz * sc; o.w = sw * sc;
  *(float4*)&actx[(size_t)row * 256 + d4] = o;
}

// ---------- l2-normalize v & actx, build x = [an, vn, an*vn] in bf16 ----------
__global__ __launch_bounds__(256) void normcat(const float* __restrict__ v,
                                               const float* __restrict__ actx,
                                               u16* __restrict__ xb) {
  const int row = blockIdx.x * 4 + (threadIdx.x >> 6);
  const int lane = threadIdx.x & 63;
  const float4 vv = *(const float4*)&v[(size_t)row * 256 + lane * 4];
  const float4 aa = *(const float4*)&actx[(size_t)row * 256 + lane * 4];
  float sv = vv.x * vv.x + vv.y * vv.y + vv.z * vv.z + vv.w * vv.w;
  float sa = aa.x * aa.x + aa.y * aa.y + aa.z * aa.z + aa.w * aa.w;
  sv = wave_bcast_sum(sv);
  sa = wave_bcast_sum(sa);
  const float iv = 1.0f / fmaxf(sqrtf(sv), 1e-8f);
  const float ia = 1.0f / fmaxf(sqrtf(sa), 1e-8f);
  const float anx = aa.x * ia, any_ = aa.y * ia, anz = aa.z * ia, anw = aa.w * ia;
  const float vnx = vv.x * iv, vny = vv.y * iv, vnz = vv.z * iv, vnw = vv.w * iv;
  u16* xr = xb + (size_t)row * 768;
  ushort4 pa, pv, pp;
  pa.x = f2bf(anx); pa.y = f2bf(any_); pa.z = f2bf(anz); pa.w = f2bf(anw);
  pv.x = f2bf(vnx); pv.y = f2bf(vny); pv.z = f2bf(vnz); pv.w = f2bf(vnw);
  pp.x = f2bf(anx * vnx); pp.y = f2bf(any_ * vny);
  pp.z = f2bf(anz * vnz); pp.w = f2bf(anw * vnw);
  *(ushort4*)&xr[lane * 4] = pa;
  *(ushort4*)&xr[256 + lane * 4] = pv;
  *(ushort4*)&xr[512 + lane * 4] = pp;
}

// ---------- final: logits = h@W2+b2, gate, fused output ----------
__global__ __launch_bounds__(256) void final_gate(const u16* __restrict__ H,
                                                  const float* __restrict__ W2,
                                                  const float* __restrict__ b2,
                                                  const float* __restrict__ actx,
                                                  const float* __restrict__ v,
                                                  float* __restrict__ out) {
  const int row = blockIdx.x * 4 + (threadIdx.x >> 6);
  const int lane = threadIdx.x & 63;
  const u16* h = H + (size_t)row * 1024 + lane * 16;
  float s = 0.0f;
#pragma unroll
  for (int u = 0; u < 16; u += 8) {
    uint4 q = *(const uint4*)&h[u];
    const float* w = &W2[lane * 16 + u];
    s += bf2f((u16)(q.x & 0xffffu)) * w[0];
    s += bf2f((u16)(q.x >> 16)) * w[1];
    s += bf2f((u16)(q.y & 0xffffu)) * w[2];
    s += bf2f((u16)(q.y >> 16)) * w[3];
    s += bf2f((u16)(q.z & 0xffffu)) * w[4];
    s += bf2f((u16)(q.z >> 16)) * w[5];
    s += bf2f((u16)(q.w & 0xffffu)) * w[6];
    s += bf2f((u16)(q.w >> 16)) * w[7];
  }
  s = wave_bcast_sum(s);
  float logit = fminf(fmaxf(s + b2[0], -12.0f), 12.0f);
  float g = 1.0f / (1.0f + expf(-logit));
  g = fminf(fmaxf(g, 0.05f), 0.95f);
  const float4 aa = *(const float4*)&actx[(size_t)row * 256 + lane * 4];
  const float4 vv = *(const float4*)&v[(size_t)row * 256 + lane * 4];
  float4 o;
  o.x = g * aa.x + (1.0f - g) * vv.x;
  o.y = g * aa.y + (1.0f - g) * vv.y;
  o.z = g * aa.z + (1.0f - g) * vv.z;
  o.w = g * aa.w + (1.0f - g) * vv.w;
  *(float4*)&out[(size_t)row * 256 + lane * 4] = o;
}

// ---------- launch ----------
extern "C" void kernel_launch(void* const* d_in, const int* in_sizes, int n_in,
                              void* d_out, int out_size, void* d_ws, size_t ws_size,
                              hipStream_t stream) {
  const float* video = (const float*)d_in[0];  // [8,2048,1024]
  const float* audio = (const float*)d_in[1];  // [8,2048,768]
  const float* Wv    = (const float*)d_in[2];  // [1024,256]
  const float* bv    = (const float*)d_in[3];  // [256]
  const float* Wa    = (const float*)d_in[4];  // [768,256]
  const float* ba    = (const float*)d_in[5];  // [256]
  const float* theta = (const float*)d_in[6];  // [1]
  const float* W1    = (const float*)d_in[7];  // [768,1024]
  const float* b1    = (const float*)d_in[8];  // [1024]
  const float* W2    = (const float*)d_in[9];  // [1024,1]
  const float* b2    = (const float*)d_in[10]; // [1]
  float* out = (float*)d_out;
  char* ws = (char*)d_ws;

  const int BT = 8 * 2048;  // 16384 rows
  // workspace layout (bytes)
  const size_t OFF_VB  = 0;                       // video bf16 [16384][1024] = 32MB; reused as H bf16 [16384][1024]
  const size_t OFF_AB  = 33554432;                // audio bf16 [16384][768] = 24MB; reused as x bf16 [16384][768]
  const size_t OFF_WVT = 58720256;                // WvT bf16 [256][1024]
  const size_t OFF_WAT = 59244544;                // WaT bf16 [256][768]
  const size_t OFF_W1T = 59637760;                // W1T bf16 [1024][768]
  const size_t OFF_V   = 61210624;                // v f32 [16384][256] = 16MB
  const size_t OFF_A   = 77987840;                // a f32 [16384][256] = 16MB
  const size_t OFF_ACTX= 94765056;                // actx f32 [16384][256] = 16MB

  u16* vb   = (u16*)(ws + OFF_VB);
  u16* ab   = (u16*)(ws + OFF_AB);
  u16* wvT  = (u16*)(ws + OFF_WVT);
  u16* waT  = (u16*)(ws + OFF_WAT);
  u16* w1T  = (u16*)(ws + OFF_W1T);
  float* v    = (float*)(ws + OFF_V);
  float* a    = (float*)(ws + OFF_A);
  float* actx = (float*)(ws + OFF_ACTX);
  u16* xb = ab;  // reuse (audio bf16 dead after GEMM2)
  u16* H  = vb;  // reuse (video bf16 dead after GEMM1)

  // 1) convert inputs to bf16
  cvt_bf16<<<(BT * 1024 / 4 + 255) / 256, 256, 0, stream>>>(video, vb, BT * 1024 / 4);
  cvt_bf16<<<(BT * 768 / 4 + 255) / 256, 256, 0, stream>>>(audio, ab, BT * 768 / 4);
  // 2) transpose+convert weights to [N][K] bf16
  tcvt<<<dim3(1024 / 32, 256 / 32), 256, 0, stream>>>(Wv, wvT, 1024, 256);
  tcvt<<<dim3(768 / 32, 256 / 32), 256, 0, stream>>>(Wa, waT, 768, 256);
  tcvt<<<dim3(768 / 32, 1024 / 32), 256, 0, stream>>>(W1, w1T, 768, 1024);
  // 3) video projection + LN
  gemm_bt<false><<<dim3(BT / 128, 256 / 128), 256, 0, stream>>>(vb, wvT, v, nullptr, BT, 256, 1024);
  ln_rows<<<BT / 4, 256, 0, stream>>>(v, bv);
  // 4) audio projection + LN
  gemm_bt<false><<<dim3(BT / 128, 256 / 128), 256, 0, stream>>>(ab, waT, a, nullptr, BT, 256, 768);
  ln_rows<<<BT / 4, 256, 0, stream>>>(a, ba);
  // 5) fractional shift + causal window average
  shift_ctx<<<BT * 64 / 256, 256, 0, stream>>>(a, actx, theta);
  // 6) l2-normalize + concat -> x bf16
  normcat<<<BT / 4, 256, 0, stream>>>(v, actx, xb);
  // 7) MLP layer 1 with fused bias+GELU -> H bf16
  gemm_bt<true><<<dim3(BT / 128, 1024 / 128), 256, 0, stream>>>(xb, w1T, H, b1, BT, 1024, 768);
  // 8) GEMV + gate + fused output
  final_gate<<<BT / 4, 256, 0, stream>>>(H, W2, b2, actx, v, out);
}

// Round 2
// 299.485 us; speedup vs baseline: 1.0623x; 1.0623x over previous
//
#include <hip/hip_runtime.h>
#include <cstdint>
#include <cstddef>

typedef unsigned short u16;
typedef unsigned int u32;
typedef __attribute__((ext_vector_type(8))) short short8;
typedef __attribute__((ext_vector_type(4))) float f32x4;

#define T_SEQ 2048

// ---------- helpers ----------
__device__ __forceinline__ u16 f2bf(float x) {
  union { float f; u32 u; } v; v.f = x;
  u32 r = v.u + 0x7fffu + ((v.u >> 16) & 1u);
  return (u16)(r >> 16);
}
__device__ __forceinline__ float bf2f(u16 h) {
  union { u32 u; float f; } v; v.u = ((u32)h) << 16;
  return v.f;
}
__device__ __forceinline__ float wave_bcast_sum(float x) {
#pragma unroll
  for (int off = 32; off > 0; off >>= 1) x += __shfl_down(x, off);
  return __shfl(x, 0);
}
__device__ __forceinline__ void gl_lds16(const void* g, void* l) {
  __builtin_amdgcn_global_load_lds((const __attribute__((address_space(1))) u32*)g,
                                   (__attribute__((address_space(3))) u32*)l, 16, 0, 0);
}
// tanh-form GELU: x*e/(e+1), e=exp(2*0.7978845608*(x+0.044715x^3))
// max |diff| vs erf-GELU ~3e-4 — below bf16 quantization of the H tensor.
__device__ __forceinline__ float gelu_f(float x) {
  float z = 1.5957691216057308f * x * (1.0f + 0.044715f * x * x);
  float e = __expf(z);
  return x - x * __builtin_amdgcn_rcpf(1.0f + e);  // z>+88: rcp(inf)=0 -> x; z<-87: rcp(1)=1 -> 0
}

// ---------- f32 -> bf16 convert (vectorized) ----------
__global__ __launch_bounds__(256) void cvt_bf16(const float* __restrict__ in,
                                                u16* __restrict__ out, int n4) {
  const int i = blockIdx.x * 256 + threadIdx.x;
  if (i >= n4) return;
  const float4 x = ((const float4*)in)[i];
  ushort4 o; o.x = f2bf(x.x); o.y = f2bf(x.y); o.z = f2bf(x.z); o.w = f2bf(x.w);
  ((ushort4*)out)[i] = o;
}

// ---------- transpose + convert: in[K][N] f32 -> out[N][K] bf16 ----------
__global__ __launch_bounds__(256) void tcvt(const float* __restrict__ in,
                                            u16* __restrict__ out, int K, int N) {
  __shared__ float tile[32][33];
  const int tx = threadIdx.x & 31;
  const int ty = threadIdx.x >> 5;
  const int k0 = blockIdx.x * 32;
  const int n0 = blockIdx.y * 32;
#pragma unroll
  for (int r = 0; r < 4; r++)
    tile[ty + r * 8][tx] = in[(size_t)(k0 + ty + r * 8) * N + n0 + tx];
  __syncthreads();
#pragma unroll
  for (int r = 0; r < 4; r++)
    out[(size_t)(n0 + ty + r * 8) * K + k0 + tx] = f2bf(tile[tx][ty + r * 8]);
}

// ---------- bf16 GEMM: C[M][N] = A[M][K] @ Bt[N][K]^T ----------
// TM in {64,128}; N-tile fixed 128.
// GELU=false: f32 C (scalar stores).  GELU=true (TM=128): LDS-staged epilogue,
// C = bf16(gelu(C + bias[col])), coalesced 16B stores.
template <int TM, bool GELU>
__global__ __launch_bounds__(256) void gemm_bt(const u16* __restrict__ A,
                                               const u16* __restrict__ Bt,
                                               void* __restrict__ Cout,
                                               const float* __restrict__ bias,
                                               int M, int N, int K) {
  constexpr int NI = TM / 32;                  // MFMA row-tiles per wave
  __shared__ u16 smem[(TM + 128) * 32];
  u16* As = smem;                              // [TM][32] row-major
  u16* Bs = smem + TM * 32;                    // [128][32] row-major
  const int tid = threadIdx.x;
  const int m0 = blockIdx.x * TM;
  const int n0 = blockIdx.y * 128;
  const int wave = tid >> 6;
  const int lane = tid & 63;
  const int qm = lane & 15;
  const int quad = lane >> 4;
  const int rw = (wave >> 1) * (TM / 2);
  const int cw = (wave & 1) * 64;

  // staging: chunk c covers row c>>2, cols (c&3)*8..+8 -> LDS offset c*16B
  const int r0 = tid >> 2, s0 = (tid & 3) * 8;
  const u16* Arow0 = A + (size_t)(m0 + r0) * K + s0;
  const u16* Arow1 = A + (size_t)(m0 + ((tid + 256) >> 2)) * K + s0;  // TM=128 only
  const u16* Brow0 = Bt + (size_t)(n0 + r0) * K + s0;
  const u16* Brow1 = Bt + (size_t)(n0 + ((tid + 256) >> 2)) * K + s0;

  f32x4 acc[NI][4] = {};

  for (int kt = 0; kt < K; kt += 32) {
    gl_lds16(Arow0 + kt, &As[tid * 8]);
    if (TM == 128) gl_lds16(Arow1 + kt, &As[(tid + 256) * 8]);
    gl_lds16(Brow0 + kt, &Bs[tid * 8]);
    gl_lds16(Brow1 + kt, &Bs[(tid + 256) * 8]);
    __syncthreads();
    short8 af[NI], bf[4];
#pragma unroll
    for (int i = 0; i < NI; i++)
      af[i] = *(const short8*)&As[(rw + i * 16 + qm) * 32 + quad * 8];
#pragma unroll
    for (int j = 0; j < 4; j++)
      bf[j] = *(const short8*)&Bs[(cw + j * 16 + qm) * 32 + quad * 8];
#pragma unroll
    for (int i = 0; i < NI; i++)
#pragma unroll
      for (int j = 0; j < 4; j++)
        acc[i][j] = __builtin_amdgcn_mfma_f32_16x16x32_bf16(af[i], bf[j], acc[i][j], 0, 0, 0);
    __syncthreads();
  }

  if constexpr (GELU) {
    // rounds of 16 rows through LDS (f32, stride 140 -> <=2-way banks both sides)
    constexpr int LST = 140;
    float* lf = (float*)smem;
    const int row16 = tid >> 4;        // 0..15
    const int cg = (tid & 15) * 8;     // 0..120
    u16* C = (u16*)Cout;
    const float4 bc0 = *(const float4*)&bias[n0 + cg];
    const float4 bc1 = *(const float4*)&bias[n0 + cg + 4];
    const float bcol[8] = {bc0.x, bc0.y, bc0.z, bc0.w, bc1.x, bc1.y, bc1.z, bc1.w};
#pragma unroll
    for (int p = 0; p < 8; p++) {
      __syncthreads();
      if ((p >> 2) == (wave >> 1)) {   // this wave-pair owns row band p*16
        const int i = p & 3;
#pragma unroll
        for (int j = 0; j < 4; j++)
#pragma unroll
          for (int r = 0; r < 4; r++)
            lf[(quad * 4 + r) * LST + cw + j * 16 + qm] = acc[i][j][r];
      }
      __syncthreads();
      float x[8];
      *(float4*)&x[0] = *(const float4*)&lf[row16 * LST + cg];
      *(float4*)&x[4] = *(const float4*)&lf[row16 * LST + cg + 4];
      u32 pk[4];
#pragma unroll
      for (int u = 0; u < 4; u++) {
        const float g0 = gelu_f(x[2 * u] + bcol[2 * u]);
        const float g1 = gelu_f(x[2 * u + 1] + bcol[2 * u + 1]);
        pk[u] = (u32)f2bf(g0) | ((u32)f2bf(g1) << 16);
      }
      *(uint4*)&C[(size_t)(m0 + p * 16 + row16) * N + n0 + cg] = *(uint4*)pk;
    }
  } else {
    float* C = (float*)Cout;
#pragma unroll
    for (int i = 0; i < NI; i++) {
      const int row = m0 + rw + i * 16 + quad * 4;  // D: row = quad*4 + reg
#pragma unroll
      for (int j = 0; j < 4; j++) {
        const int col = n0 + cw + j * 16 + qm;      // D: col = lane&15
#pragma unroll
        for (int r = 0; r < 4; r++)
          C[(size_t)(row + r) * N + col] = acc[i][j][r];
      }
    }
  }
}

// ---------- in-place layernorm over 256 cols, with bias added first ----------
__global__ __launch_bounds__(256) void ln_rows(float* __restrict__ X,
                                               const float* __restrict__ bias) {
  const int row = blockIdx.x * 4 + (threadIdx.x >> 6);
  const int lane = threadIdx.x & 63;
  float4 x = *(float4*)&X[(size_t)row * 256 + lane * 4];
  const float4 b = *(const float4*)&bias[lane * 4];
  x.x += b.x; x.y += b.y; x.z += b.z; x.w += b.w;
  float s = x.x + x.y + x.z + x.w;
  float s2 = x.x * x.x + x.y * x.y + x.z * x.z + x.w * x.w;
  s = wave_bcast_sum(s);
  s2 = wave_bcast_sum(s2);
  const float mu = s * (1.0f / 256.0f);
  const float var = s2 * (1.0f / 256.0f) - mu * mu;
  const float inv = rsqrtf(var + 1e-5f);
  x.x = (x.x - mu) * inv; x.y = (x.y - mu) * inv;
  x.z = (x.z - mu) * inv; x.w = (x.w - mu) * inv;
  *(float4*)&X[(size_t)row * 256 + lane * 4] = x;
}

// ---------- fused: fractional shift + window avg + l2norm(actx,v) + concat ----------
__global__ __launch_bounds__(256) void shift_norm(const float* __restrict__ a,
                                                  const float* __restrict__ v,
                                                  float* __restrict__ actx,
                                                  u16* __restrict__ xb,
                                                  const float* __restrict__ theta) {
  const int row = blockIdx.x * 4 + (threadIdx.x >> 6);  // one wave per row
  const int lane = threadIdx.x & 63;
  const int d4 = lane * 4;
  const int bb = row >> 11;          // T=2048
  const int t = row & (T_SEQ - 1);
  const float th = fminf(fmaxf(theta[0], -12.0f), 12.0f);
  const float delta = 2.0f + 4.0f * (1.0f / (1.0f + expf(-th)));
  const float dl = fminf(fmaxf(delta, 0.0f), (float)(T_SEQ - 1));
  const float nf = floorf(dl);
  const float alpha = dl - nf;
  const int ni = (int)nf;
  const float center = fminf(fmaxf((float)t + delta, 0.0f), (float)t);
  float sx = 0, sy = 0, sz = 0, sw = 0, cnt = 0.0f;
  const float* ab = a + (size_t)bb * T_SEQ * 256;
#pragma unroll
  for (int j = 0; j < 6; j++) {
    const int tau = t - 5 + j;
    if (tau < 0) continue;
    if (fabsf((float)tau - center) > 5.0f) continue;  // tau<=t by construction
    cnt += 1.0f;
    const int i0 = min(max(tau - ni, 0), T_SEQ - 1);
    const int i1 = min(i0 + 1, T_SEQ - 1);
    const float4 a0 = *(const float4*)&ab[(size_t)i0 * 256 + d4];
    const float4 a1 = *(const float4*)&ab[(size_t)i1 * 256 + d4];
    sx += a0.x + alpha * (a1.x - a0.x);
    sy += a0.y + alpha * (a1.y - a0.y);
    sz += a0.z + alpha * (a1.z - a0.z);
    sw += a0.w + alpha * (a1.w - a0.w);
  }
  const float sc = 1.0f / fmaxf(cnt, 1e-8f);
  float4 o; o.x = sx * sc; o.y = sy * sc; o.z = sz * sc; o.w = sw * sc;
  *(float4*)&actx[(size_t)row * 256 + d4] = o;
  // l2-normalize actx & v, emit x = [an, vn, an*vn] bf16
  const float4 vv = *(const float4*)&v[(size_t)row * 256 + d4];
  float sa2 = o.x * o.x + o.y * o.y + o.z * o.z + o.w * o.w;
  float sv2 = vv.x * vv.x + vv.y * vv.y + vv.z * vv.z + vv.w * vv.w;
  sa2 = wave_bcast_sum(sa2);
  sv2 = wave_bcast_sum(sv2);
  const float ia = 1.0f / fmaxf(sqrtf(sa2), 1e-8f);
  const float iv = 1.0f / fmaxf(sqrtf(sv2), 1e-8f);
  const float anx = o.x * ia, any_ = o.y * ia, anz = o.z * ia, anw = o.w * ia;
  const float vnx = vv.x * iv, vny = vv.y * iv, vnz = vv.z * iv, vnw = vv.w * iv;
  u16* xr = xb + (size_t)row * 768;
  ushort4 pa, pv, pp;
  pa.x = f2bf(anx); pa.y = f2bf(any_); pa.z = f2bf(anz); pa.w = f2bf(anw);
  pv.x = f2bf(vnx); pv.y = f2bf(vny); pv.z = f2bf(vnz); pv.w = f2bf(vnw);
  pp.x = f2bf(anx * vnx); pp.y = f2bf(any_ * vny);
  pp.z = f2bf(anz * vnz); pp.w = f2bf(anw * vnw);
  *(ushort4*)&xr[d4] = pa;
  *(ushort4*)&xr[256 + d4] = pv;
  *(ushort4*)&xr[512 + d4] = pp;
}

// ---------- final: logits = h@W2+b2, gate, fused output ----------
__global__ __launch_bounds__(256) void final_gate(const u16* __restrict__ H,
                                                  const float* __restrict__ W2,
                                                  const float* __restrict__ b2,
                                                  const float* __restrict__ actx,
                                                  const float* __restrict__ v,
                                                  float* __restrict__ out) {
  const int row = blockIdx.x * 4 + (threadIdx.x >> 6);
  const int lane = threadIdx.x & 63;
  const u16* h = H + (size_t)row * 1024 + lane * 16;
  float s = 0.0f;
#pragma unroll
  for (int u = 0; u < 16; u += 8) {
    uint4 q = *(const uint4*)&h[u];
    const float* w = &W2[lane * 16 + u];
    s += bf2f((u16)(q.x & 0xffffu)) * w[0];
    s += bf2f((u16)(q.x >> 16)) * w[1];
    s += bf2f((u16)(q.y & 0xffffu)) * w[2];
    s += bf2f((u16)(q.y >> 16)) * w[3];
    s += bf2f((u16)(q.z & 0xffffu)) * w[4];
    s += bf2f((u16)(q.z >> 16)) * w[5];
    s += bf2f((u16)(q.w & 0xffffu)) * w[6];
    s += bf2f((u16)(q.w >> 16)) * w[7];
  }
  s = wave_bcast_sum(s);
  float logit = fminf(fmaxf(s + b2[0], -12.0f), 12.0f);
  float g = 1.0f / (1.0f + expf(-logit));
  g = fminf(fmaxf(g, 0.05f), 0.95f);
  const float4 aa = *(const float4*)&actx[(size_t)row * 256 + lane * 4];
  const float4 vv = *(const float4*)&v[(size_t)row * 256 + lane * 4];
  float4 o;
  o.x = g * aa.x + (1.0f - g) * vv.x;
  o.y = g * aa.y + (1.0f - g) * vv.y;
  o.z = g * aa.z + (1.0f - g) * vv.z;
  o.w = g * aa.w + (1.0f - g) * vv.w;
  *(float4*)&out[(size_t)row * 256 + lane * 4] = o;
}

// ---------- launch ----------
extern "C" void kernel_launch(void* const* d_in, const int* in_sizes, int n_in,
                              void* d_out, int out_size, void* d_ws, size_t ws_size,
                              hipStream_t stream) {
  const float* video = (const float*)d_in[0];  // [8,2048,1024]
  const float* audio = (const float*)d_in[1];  // [8,2048,768]
  const float* Wv    = (const float*)d_in[2];  // [1024,256]
  const float* bv    = (const float*)d_in[3];  // [256]
  const float* Wa    = (const float*)d_in[4];  // [768,256]
  const float* ba    = (const float*)d_in[5];  // [256]
  const float* theta = (const float*)d_in[6];  // [1]
  const float* W1    = (const float*)d_in[7];  // [768,1024]
  const float* b1    = (const float*)d_in[8];  // [1024]
  const float* W2    = (const float*)d_in[9];  // [1024,1]
  const float* b2    = (const float*)d_in[10]; // [1]
  float* out = (float*)d_out;
  char* ws = (char*)d_ws;

  const int BT = 8 * 2048;  // 16384 rows
  const size_t OFF_VB  = 0;         // video bf16 32MB; reused as H bf16
  const size_t OFF_AB  = 33554432;  // audio bf16 24MB; reused as x bf16
  const size_t OFF_WVT = 58720256;  // WvT bf16 [256][1024]
  const size_t OFF_WAT = 59244544;  // WaT bf16 [256][768]
  const size_t OFF_W1T = 59637760;  // W1T bf16 [1024][768]
  const size_t OFF_V   = 61210624;  // v f32 16MB
  const size_t OFF_A   = 77987840;  // a f32 16MB
  const size_t OFF_ACTX= 94765056;  // actx f32 16MB

  u16* vb   = (u16*)(ws + OFF_VB);
  u16* ab   = (u16*)(ws + OFF_AB);
  u16* wvT  = (u16*)(ws + OFF_WVT);
  u16* waT  = (u16*)(ws + OFF_WAT);
  u16* w1T  = (u16*)(ws + OFF_W1T);
  float* v    = (float*)(ws + OFF_V);
  float* a    = (float*)(ws + OFF_A);
  float* actx = (float*)(ws + OFF_ACTX);
  u16* xb = ab;  // reuse
  u16* H  = vb;  // reuse

  cvt_bf16<<<(BT * 1024 / 4 + 255) / 256, 256, 0, stream>>>(video, vb, BT * 1024 / 4);
  cvt_bf16<<<(BT * 768 / 4 + 255) / 256, 256, 0, stream>>>(audio, ab, BT * 768 / 4);
  tcvt<<<dim3(1024 / 32, 256 / 32), 256, 0, stream>>>(Wv, wvT, 1024, 256);
  tcvt<<<dim3(768 / 32, 256 / 32), 256, 0, stream>>>(Wa, waT, 768, 256);
  tcvt<<<dim3(768 / 32, 1024 / 32), 256, 0, stream>>>(W1, w1T, 768, 1024);
  // projections: TM=64 -> 512 blocks = 2 blocks/CU for latency overlap
  gemm_bt<64, false><<<dim3(BT / 64, 2), 256, 0, stream>>>(vb, wvT, v, nullptr, BT, 256, 1024);
  ln_rows<<<BT / 4, 256, 0, stream>>>(v, bv);
  gemm_bt<64, false><<<dim3(BT / 64, 2), 256, 0, stream>>>(ab, waT, a, nullptr, BT, 256, 768);
  ln_rows<<<BT / 4, 256, 0, stream>>>(a, ba);
  shift_norm<<<BT / 4, 256, 0, stream>>>(a, v, actx, xb, theta);
  gemm_bt<128, true><<<dim3(BT / 128, 8), 256, 0, stream>>>(xb, w1T, H, b1, BT, 1024, 768);
  final_gate<<<BT / 4, 256, 0, stream>>>(H, W2, b2, actx, v, out);
}

// Round 3
// 293.092 us; speedup vs baseline: 1.0854x; 1.0218x over previous
//
#include <hip/hip_runtime.h>
#include <cstdint>
#include <cstddef>

typedef unsigned short u16;
typedef unsigned int u32;
typedef __attribute__((ext_vector_type(8))) short short8;
typedef __attribute__((ext_vector_type(4))) float f32x4;

#define T_SEQ 2048
#define BT_ROWS 16384

// ---------- helpers ----------
__device__ __forceinline__ u16 f2bf(float x) {
  union { float f; u32 u; } v; v.f = x;
  u32 r = v.u + 0x7fffu + ((v.u >> 16) & 1u);
  return (u16)(r >> 16);
}
__device__ __forceinline__ float wave_bcast_sum(float x) {
#pragma unroll
  for (int off = 32; off > 0; off >>= 1) x += __shfl_down(x, off);
  return __shfl(x, 0);
}
__device__ __forceinline__ void gl_lds16(const void* g, void* l) {
  __builtin_amdgcn_global_load_lds((const __attribute__((address_space(1))) u32*)g,
                                   (__attribute__((address_space(3))) u32*)l, 16, 0, 0);
}
// tanh-form GELU: x - x/(1+e^z), z = 2*0.7978845608*(x+0.044715x^3); |diff| vs erf ~3e-4
__device__ __forceinline__ float gelu_f(float x) {
  float z = 1.5957691216057308f * x * (1.0f + 0.044715f * x * x);
  float e = __expf(z);
  return x - x * __builtin_amdgcn_rcpf(1.0f + e);
}
__device__ __forceinline__ short8 pack_bf8(const float* f) {
  short8 s;
#pragma unroll
  for (int e = 0; e < 8; e++) s[e] = (short)f2bf(f[e]);
  return s;
}

// ---------- fused transpose+convert of all 3 weights: [K][N] f32 -> [N][K] bf16 ----------
__global__ __launch_bounds__(256) void tcvt_all(const float* __restrict__ Wv,
                                                const float* __restrict__ Wa,
                                                const float* __restrict__ W1,
                                                u16* __restrict__ wvT,
                                                u16* __restrict__ waT,
                                                u16* __restrict__ w1T) {
  __shared__ float tile[32][33];
  int b = blockIdx.x;
  const float* in; u16* out; int K, N, bx, by;
  if (b < 256)      { in = Wv; out = wvT; K = 1024; N = 256;  bx = b & 31;  by = b >> 5; }
  else if (b < 448) { b -= 256; in = Wa; out = waT; K = 768; N = 256;  bx = b % 24; by = b / 24; }
  else              { b -= 448; in = W1; out = w1T; K = 768; N = 1024; bx = b % 24; by = b / 24; }
  const int k0 = bx * 32, n0 = by * 32;
  const int tx = threadIdx.x & 31, ty = threadIdx.x >> 5;
#pragma unroll
  for (int r = 0; r < 4; r++)
    tile[ty + r * 8][tx] = in[(size_t)(k0 + ty + r * 8) * N + n0 + tx];
  __syncthreads();
#pragma unroll
  for (int r = 0; r < 4; r++)
    out[(size_t)(n0 + ty + r * 8) * K + k0 + tx] = f2bf(tile[tx][ty + r * 8]);
}

// ---------- projection GEMM: C[M][256] f32 = A[M][K] f32 @ Bt[256][K] bf16^T ----------
// A staged as f32 into LDS (XOR-swizzled 16B chunks), converted to bf16 at frag read.
// Tile 64x128; n0 from blockIdx.x&1 so adjacent blocks share the A-tile (L2/L3 reuse).
__global__ __launch_bounds__(256) void gemm_f32a(const float* __restrict__ A,
                                                 const u16* __restrict__ Bt,
                                                 float* __restrict__ C, int K) {
  __shared__ float Asf[64 * 32];   // 8 KB
  __shared__ u16 Bs[128 * 32];     // 8 KB
  const int tid = threadIdx.x;
  const int m0 = (blockIdx.x >> 1) * 64;
  const int n0 = (blockIdx.x & 1) * 128;
  const int wave = tid >> 6, lane = tid & 63, qm = lane & 15, quad = lane >> 4;
  const int rw = (wave >> 1) * 32, cw = (wave & 1) * 64;
  // A chunks: 4 f32 each; LDS slot tid holds global q = (tid&7)^((tid>>3)&7) of row tid>>3
  const int aq = ((tid & 7) ^ ((tid >> 3) & 7)) * 4;
  const float* Ar0 = A + (size_t)(m0 + (tid >> 3)) * K + aq;
  const float* Ar1 = A + (size_t)(m0 + (tid >> 3) + 32) * K + aq;
  // B chunks: 8 bf16 each; slot q = (tid&3)^((tid>>2)&3)
  const int bq = ((tid & 3) ^ ((tid >> 2) & 3)) * 8;
  const u16* Br0 = Bt + (size_t)(n0 + (tid >> 2)) * K + bq;
  const u16* Br1 = Bt + (size_t)(n0 + (tid >> 2) + 64) * K + bq;

  f32x4 acc[2][4] = {};
  for (int kt = 0; kt < K; kt += 32) {
    gl_lds16(Ar0 + kt, &Asf[tid * 4]);
    gl_lds16(Ar1 + kt, &Asf[(tid + 256) * 4]);
    gl_lds16(Br0 + kt, &Bs[tid * 8]);
    gl_lds16(Br1 + kt, &Bs[(tid + 256) * 8]);
    __syncthreads();
    short8 af[2], bfr[4];
#pragma unroll
    for (int i = 0; i < 2; i++) {
      const int ar = rw + i * 16 + qm;
      float f[8];
      *(float4*)&f[0] = *(const float4*)&Asf[(ar * 8 + ((quad * 2) ^ (ar & 7))) * 4];
      *(float4*)&f[4] = *(const float4*)&Asf[(ar * 8 + ((quad * 2 + 1) ^ (ar & 7))) * 4];
      af[i] = pack_bf8(f);
    }
#pragma unroll
    for (int j = 0; j < 4; j++) {
      const int br = cw + j * 16 + qm;
      bfr[j] = *(const short8*)&Bs[(br * 4 + (quad ^ (br & 3))) * 8];
    }
#pragma unroll
    for (int i = 0; i < 2; i++)
#pragma unroll
      for (int j = 0; j < 4; j++)
        acc[i][j] = __builtin_amdgcn_mfma_f32_16x16x32_bf16(af[i], bfr[j], acc[i][j], 0, 0, 0);
    __syncthreads();
  }
#pragma unroll
  for (int i = 0; i < 2; i++) {
    const int row = m0 + rw + i * 16 + quad * 4;   // D: row = quad*4 + reg
#pragma unroll
    for (int j = 0; j < 4; j++) {
      const int col = n0 + cw + j * 16 + qm;       // D: col = lane&15
#pragma unroll
      for (int r = 0; r < 4; r++)
        C[(size_t)(row + r) * 256 + col] = acc[i][j][r];
    }
  }
}

// ---------- MLP GEMM with fused bias+GELU+W2 partial dot -> atomic logits ----------
// A = x bf16 [M][768], Bt = W1^T bf16 [1024][768]. No H tensor at all.
__global__ __launch_bounds__(256) void gemm_gelu_w2(const u16* __restrict__ A,
                                                    const u16* __restrict__ Bt,
                                                    const float* __restrict__ b1,
                                                    const float* __restrict__ W2,
                                                    float* __restrict__ logits, int K) {
  __shared__ u16 As[128 * 32];
  __shared__ u16 Bs[128 * 32];
  const int tid = threadIdx.x;
  const int m0 = blockIdx.x * 128;
  const int n0 = blockIdx.y * 128;
  const int wave = tid >> 6, lane = tid & 63, qm = lane & 15, quad = lane >> 4;
  const int rw = (wave >> 1) * 64, cw = (wave & 1) * 64;
  const int cq = ((tid & 3) ^ ((tid >> 2) & 3)) * 8;
  const u16* Ar0 = A + (size_t)(m0 + (tid >> 2)) * K + cq;
  const u16* Ar1 = A + (size_t)(m0 + (tid >> 2) + 64) * K + cq;
  const u16* Br0 = Bt + (size_t)(n0 + (tid >> 2)) * K + cq;
  const u16* Br1 = Bt + (size_t)(n0 + (tid >> 2) + 64) * K + cq;

  f32x4 acc[4][4] = {};
  for (int kt = 0; kt < K; kt += 32) {
    gl_lds16(Ar0 + kt, &As[tid * 8]);
    gl_lds16(Ar1 + kt, &As[(tid + 256) * 8]);
    gl_lds16(Br0 + kt, &Bs[tid * 8]);
    gl_lds16(Br1 + kt, &Bs[(tid + 256) * 8]);
    __syncthreads();
    short8 af[4], bfr[4];
#pragma unroll
    for (int i = 0; i < 4; i++) {
      const int ar = rw + i * 16 + qm;
      af[i] = *(const short8*)&As[(ar * 4 + (quad ^ (ar & 3))) * 8];
    }
#pragma unroll
    for (int j = 0; j < 4; j++) {
      const int br = cw + j * 16 + qm;
      bfr[j] = *(const short8*)&Bs[(br * 4 + (quad ^ (br & 3))) * 8];
    }
#pragma unroll
    for (int i = 0; i < 4; i++)
#pragma unroll
      for (int j = 0; j < 4; j++)
        acc[i][j] = __builtin_amdgcn_mfma_f32_16x16x32_bf16(af[i], bfr[j], acc[i][j], 0, 0, 0);
    __syncthreads();
  }

  // epilogue: partial logit = sum_j gelu(acc+b1[col]) * W2[col]; reduce over 16 qm lanes
  float w2j[4], bc[4];
#pragma unroll
  for (int j = 0; j < 4; j++) {
    const int col = n0 + cw + j * 16 + qm;
    w2j[j] = W2[col];
    bc[j] = b1[col];
  }
#pragma unroll
  for (int i = 0; i < 4; i++) {
#pragma unroll
    for (int r = 0; r < 4; r++) {
      float p = 0.0f;
#pragma unroll
      for (int j = 0; j < 4; j++)
        p += gelu_f(acc[i][j][r] + bc[j]) * w2j[j];
      p += __shfl_xor(p, 1);
      p += __shfl_xor(p, 2);
      p += __shfl_xor(p, 4);
      p += __shfl_xor(p, 8);
      if (qm == 0)
        atomicAdd(&logits[m0 + rw + i * 16 + quad * 4 + r], p);
    }
  }
}

// ---------- layernorm (bias added first) over both v and a ----------
__global__ __launch_bounds__(256) void ln2(float* __restrict__ v, float* __restrict__ a,
                                           const float* __restrict__ bv,
                                           const float* __restrict__ ba) {
  const int gr = blockIdx.x * 4 + (threadIdx.x >> 6);
  const int lane = threadIdx.x & 63;
  float* X; const float* bias; int row;
  if (gr < BT_ROWS) { X = v; bias = bv; row = gr; }
  else              { X = a; bias = ba; row = gr - BT_ROWS; }
  float4 x = *(float4*)&X[(size_t)row * 256 + lane * 4];
  const float4 b = *(const float4*)&bias[lane * 4];
  x.x += b.x; x.y += b.y; x.z += b.z; x.w += b.w;
  float s = x.x + x.y + x.z + x.w;
  float s2 = x.x * x.x + x.y * x.y + x.z * x.z + x.w * x.w;
  s = wave_bcast_sum(s);
  s2 = wave_bcast_sum(s2);
  const float mu = s * (1.0f / 256.0f);
  const float var = s2 * (1.0f / 256.0f) - mu * mu;
  const float inv = rsqrtf(var + 1e-5f);
  x.x = (x.x - mu) * inv; x.y = (x.y - mu) * inv;
  x.z = (x.z - mu) * inv; x.w = (x.w - mu) * inv;
  *(float4*)&X[(size_t)row * 256 + lane * 4] = x;
}

// ---------- fused: fractional shift + window avg + l2norm(actx,v) + concat ----------
__global__ __launch_bounds__(256) void shift_norm(const float* __restrict__ a,
                                                  const float* __restrict__ v,
                                                  float* __restrict__ actx,
                                                  u16* __restrict__ xb,
                                                  const float* __restrict__ theta) {
  const int row = blockIdx.x * 4 + (threadIdx.x >> 6);
  const int lane = threadIdx.x & 63;
  const int d4 = lane * 4;
  const int bb = row >> 11;
  const int t = row & (T_SEQ - 1);
  const float th = fminf(fmaxf(theta[0], -12.0f), 12.0f);
  const float delta = 2.0f + 4.0f * (1.0f / (1.0f + expf(-th)));
  const float dl = fminf(fmaxf(delta, 0.0f), (float)(T_SEQ - 1));
  const float nf = floorf(dl);
  const float alpha = dl - nf;
  const int ni = (int)nf;
  const float center = fminf(fmaxf((float)t + delta, 0.0f), (float)t);
  float sx = 0, sy = 0, sz = 0, sw = 0, cnt = 0.0f;
  const float* ab = a + (size_t)bb * T_SEQ * 256;
#pragma unroll
  for (int j = 0; j < 6; j++) {
    const int tau = t - 5 + j;
    if (tau < 0) continue;
    if (fabsf((float)tau - center) > 5.0f) continue;
    cnt += 1.0f;
    const int i0 = min(max(tau - ni, 0), T_SEQ - 1);
    const int i1 = min(i0 + 1, T_SEQ - 1);
    const float4 a0 = *(const float4*)&ab[(size_t)i0 * 256 + d4];
    const float4 a1 = *(const float4*)&ab[(size_t)i1 * 256 + d4];
    sx += a0.x + alpha * (a1.x - a0.x);
    sy += a0.y + alpha * (a1.y - a0.y);
    sz += a0.z + alpha * (a1.z - a0.z);
    sw += a0.w + alpha * (a1.w - a0.w);
  }
  const float sc = 1.0f / fmaxf(cnt, 1e-8f);
  float4 o; o.x = sx * sc; o.y = sy * sc; o.z = sz * sc; o.w = sw * sc;
  *(float4*)&actx[(size_t)row * 256 + d4] = o;
  const float4 vv = *(const float4*)&v[(size_t)row * 256 + d4];
  float sa2 = o.x * o.x + o.y * o.y + o.z * o.z + o.w * o.w;
  float sv2 = vv.x * vv.x + vv.y * vv.y + vv.z * vv.z + vv.w * vv.w;
  sa2 = wave_bcast_sum(sa2);
  sv2 = wave_bcast_sum(sv2);
  const float ia = 1.0f / fmaxf(sqrtf(sa2), 1e-8f);
  const float iv = 1.0f / fmaxf(sqrtf(sv2), 1e-8f);
  const float anx = o.x * ia, any_ = o.y * ia, anz = o.z * ia, anw = o.w * ia;
  const float vnx = vv.x * iv, vny = vv.y * iv, vnz = vv.z * iv, vnw = vv.w * iv;
  u16* xr = xb + (size_t)row * 768;
  ushort4 pa, pv, pp;
  pa.x = f2bf(anx); pa.y = f2bf(any_); pa.z = f2bf(anz); pa.w = f2bf(anw);
  pv.x = f2bf(vnx); pv.y = f2bf(vny); pv.z = f2bf(vnz); pv.w = f2bf(vnw);
  pp.x = f2bf(anx * vnx); pp.y = f2bf(any_ * vny);
  pp.z = f2bf(anz * vnz); pp.w = f2bf(anw * vnw);
  *(ushort4*)&xr[d4] = pa;
  *(ushort4*)&xr[256 + d4] = pv;
  *(ushort4*)&xr[512 + d4] = pp;
}

// ---------- gate + mix ----------
__global__ __launch_bounds__(256) void gate_mix(const float* __restrict__ logits,
                                                const float* __restrict__ b2,
                                                const float* __restrict__ actx,
                                                const float* __restrict__ v,
                                                float* __restrict__ out) {
  const int row = blockIdx.x * 4 + (threadIdx.x >> 6);
  const int lane = threadIdx.x & 63;
  const float l = fminf(fmaxf(logits[row] + b2[0], -12.0f), 12.0f);
  float g = 1.0f / (1.0f + expf(-l));
  g = fminf(fmaxf(g, 0.05f), 0.95f);
  const float4 aa = *(const float4*)&actx[(size_t)row * 256 + lane * 4];
  const float4 vv = *(const float4*)&v[(size_t)row * 256 + lane * 4];
  float4 o;
  o.x = g * aa.x + (1.0f - g) * vv.x;
  o.y = g * aa.y + (1.0f - g) * vv.y;
  o.z = g * aa.z + (1.0f - g) * vv.z;
  o.w = g * aa.w + (1.0f - g) * vv.w;
  *(float4*)&out[(size_t)row * 256 + lane * 4] = o;
}

// ---------- launch ----------
extern "C" void kernel_launch(void* const* d_in, const int* in_sizes, int n_in,
                              void* d_out, int out_size, void* d_ws, size_t ws_size,
                              hipStream_t stream) {
  const float* video = (const float*)d_in[0];
  const float* audio = (const float*)d_in[1];
  const float* Wv    = (const float*)d_in[2];
  const float* bv    = (const float*)d_in[3];
  const float* Wa    = (const float*)d_in[4];
  const float* ba    = (const float*)d_in[5];
  const float* theta = (const float*)d_in[6];
  const float* W1    = (const float*)d_in[7];
  const float* b1    = (const float*)d_in[8];
  const float* W2    = (const float*)d_in[9];
  const float* b2    = (const float*)d_in[10];
  float* out = (float*)d_out;
  char* ws = (char*)d_ws;

  // workspace layout
  const size_t OFF_WVT = 0;          // [256][1024] bf16 = 512 KB
  const size_t OFF_WAT = 524288;     // [256][768]  bf16 = 384 KB
  const size_t OFF_W1T = 917504;     // [1024][768] bf16 = 1.5 MB
  const size_t OFF_LOG = 2490368;    // [16384] f32 = 64 KB
  const size_t OFF_V   = 2555904;    // [16384][256] f32 = 16 MB
  const size_t OFF_A   = 19333120;   // [16384][256] f32 = 16 MB
  const size_t OFF_ACTX= 36110336;   // [16384][256] f32 = 16 MB
  const size_t OFF_XB  = 52887552;   // [16384][768] bf16 = 24 MB

  u16* wvT = (u16*)(ws + OFF_WVT);
  u16* waT = (u16*)(ws + OFF_WAT);
  u16* w1T = (u16*)(ws + OFF_W1T);
  float* logits = (float*)(ws + OFF_LOG);
  float* v    = (float*)(ws + OFF_V);
  float* a    = (float*)(ws + OFF_A);
  float* actx = (float*)(ws + OFF_ACTX);
  u16* xb = (u16*)(ws + OFF_XB);

  tcvt_all<<<1216, 256, 0, stream>>>(Wv, Wa, W1, wvT, waT, w1T);
  hipMemsetAsync(logits, 0, BT_ROWS * sizeof(float), stream);
  gemm_f32a<<<BT_ROWS / 64 * 2, 256, 0, stream>>>(video, wvT, v, 1024);
  gemm_f32a<<<BT_ROWS / 64 * 2, 256, 0, stream>>>(audio, waT, a, 768);
  ln2<<<2 * BT_ROWS / 4, 256, 0, stream>>>(v, a, bv, ba);
  shift_norm<<<BT_ROWS / 4, 256, 0, stream>>>(a, v, actx, xb, theta);
  gemm_gelu_w2<<<dim3(BT_ROWS / 128, 8), 256, 0, stream>>>(xb, w1T, b1, W2, logits, 768);
  gate_mix<<<BT_ROWS / 4, 256, 0, stream>>>(logits, b2, actx, v, out);
}

// Round 4
// 259.304 us; speedup vs baseline: 1.2269x; 1.1303x over previous
//
#include <hip/hip_runtime.h>
#include <cstdint>
#include <cstddef>

typedef unsigned short u16;
typedef unsigned int u32;
typedef __attribute__((ext_vector_type(8))) short short8;
typedef __attribute__((ext_vector_type(4))) float f32x4;

#define T_SEQ 2048
#define BT_ROWS 16384

// ---------- helpers ----------
__device__ __forceinline__ u16 f2bf(float x) {
  union { float f; u32 u; } v; v.f = x;
  u32 r = v.u + 0x7fffu + ((v.u >> 16) & 1u);
  return (u16)(r >> 16);
}
// pack two floats -> two bf16 in one u32 (lo in low half): 2x round + v_perm
__device__ __forceinline__ u32 pkbf(float lo, float hi) {
  union { float f; u32 u; } a, b; a.f = lo; b.f = hi;
  const u32 ra = a.u + 0x7fffu + ((a.u >> 16) & 1u);
  const u32 rb = b.u + 0x7fffu + ((b.u >> 16) & 1u);
  return __builtin_amdgcn_perm(rb, ra, 0x07060302);  // {rb_hi, ra_hi}
}
__device__ __forceinline__ float wave_bcast_sum(float x) {
#pragma unroll
  for (int off = 32; off > 0; off >>= 1) x += __shfl_down(x, off);
  return __shfl(x, 0);
}
__device__ __forceinline__ void gl_lds16(const void* g, void* l) {
  __builtin_amdgcn_global_load_lds((const __attribute__((address_space(1))) u32*)g,
                                   (__attribute__((address_space(3))) u32*)l, 16, 0, 0);
}
// tanh-form GELU; |diff| vs erf ~3e-4
__device__ __forceinline__ float gelu_f(float x) {
  float z = 1.5957691216057308f * x * (1.0f + 0.044715f * x * x);
  float e = __expf(z);
  return x - x * __builtin_amdgcn_rcpf(1.0f + e);
}

// ---------- fused transpose+convert of all 3 weights: [K][N] f32 -> [N][K] bf16 ----------
__global__ __launch_bounds__(256) void tcvt_all(const float* __restrict__ Wv,
                                                const float* __restrict__ Wa,
                                                const float* __restrict__ W1,
                                                u16* __restrict__ wvT,
                                                u16* __restrict__ waT,
                                                u16* __restrict__ w1T) {
  __shared__ float tile[32][33];
  int b = blockIdx.x;
  const float* in; u16* out; int K, N, bx, by;
  if (b < 256)      { in = Wv; out = wvT; K = 1024; N = 256;  bx = b & 31;  by = b >> 5; }
  else if (b < 448) { b -= 256; in = Wa; out = waT; K = 768; N = 256;  bx = b % 24; by = b / 24; }
  else              { b -= 448; in = W1; out = w1T; K = 768; N = 1024; bx = b % 24; by = b / 24; }
  const int k0 = bx * 32, n0 = by * 32;
  const int tx = threadIdx.x & 31, ty = threadIdx.x >> 5;
#pragma unroll
  for (int r = 0; r < 4; r++)
    tile[ty + r * 8][tx] = in[(size_t)(k0 + ty + r * 8) * N + n0 + tx];
  __syncthreads();
#pragma unroll
  for (int r = 0; r < 4; r++)
    out[(size_t)(n0 + ty + r * 8) * K + k0 + tx] = f2bf(tile[tx][ty + r * 8]);
}

// ---------- merged projection GEMM: C[M][256] f32 = A[M][K] f32 @ Bt[256][K] bf16^T ----------
// Tile 64x128, BK=64, A staged f32 (XOR-swizzled 16B chunks), pk-converted at frag read.
// Blocks 0..511: video (K=1024); 512..1023: audio (K=768). 1024 blocks co-resident.
__global__ __launch_bounds__(256, 5) void gemm_proj(const float* __restrict__ Vin,
                                                    const float* __restrict__ Ain,
                                                    const u16* __restrict__ wvT,
                                                    const u16* __restrict__ waT,
                                                    float* __restrict__ Cv,
                                                    float* __restrict__ Ca) {
  __shared__ float Asf[64 * 64];   // 16 KB
  __shared__ u16 Bs[128 * 64];     // 16 KB
  int b = blockIdx.x;
  const float* A; const u16* Bt; float* C; int K;
  if (b < 512) { A = Vin; Bt = wvT; C = Cv; K = 1024; }
  else         { b -= 512; A = Ain; Bt = waT; C = Ca; K = 768; }
  const int m0 = (b >> 1) * 64;
  const int n0 = (b & 1) * 128;
  const int tid = threadIdx.x;
  const int wave = tid >> 6, lane = tid & 63, qm = lane & 15, quad = lane >> 4;
  const int rw = (wave >> 1) * 32, cw = (wave & 1) * 64;

  // staging: A chunk c -> row c>>4, swizzled f32-part (c&15)^(row&15); LDS byte c*16
  const int arow = tid >> 4;
  const int apart = (tid & 15) ^ (arow & 15);
  const float* Ap[4];
#pragma unroll
  for (int g = 0; g < 4; g++)
    Ap[g] = A + (size_t)(m0 + arow + g * 16) * K + apart * 4;
  // B chunk c -> row c>>3, swizzled 16B-part (c&7)^(row&7)
  const int brow = tid >> 3;
  const int bpart = (tid & 7) ^ (brow & 7);
  const u16* Bp[4];
#pragma unroll
  for (int g = 0; g < 4; g++)
    Bp[g] = Bt + (size_t)(n0 + brow + g * 32) * K + bpart * 8;

  f32x4 acc[2][4] = {};
  for (int kt = 0; kt < K; kt += 64) {
#pragma unroll
    for (int g = 0; g < 4; g++) gl_lds16(Ap[g] + kt, &Asf[(tid + g * 256) * 4]);
#pragma unroll
    for (int g = 0; g < 4; g++) gl_lds16(Bp[g] + kt, &Bs[(tid + g * 256) * 8]);
    __syncthreads();
#pragma unroll
    for (int s = 0; s < 2; s++) {
      short8 af[2], bfr[4];
#pragma unroll
      for (int i = 0; i < 2; i++) {
        const int r = rw + i * 16 + qm;
        const int pb = s * 8 + quad * 2;
        const float4 f0 = *(const float4*)&Asf[r * 64 + ((pb) ^ (r & 15)) * 4];
        const float4 f1 = *(const float4*)&Asf[r * 64 + ((pb + 1) ^ (r & 15)) * 4];
        u32 w[4] = {pkbf(f0.x, f0.y), pkbf(f0.z, f0.w), pkbf(f1.x, f1.y), pkbf(f1.z, f1.w)};
        af[i] = *(short8*)w;
      }
#pragma unroll
      for (int j = 0; j < 4; j++) {
        const int r = cw + j * 16 + qm;
        bfr[j] = *(const short8*)&Bs[r * 64 + ((s * 4 + quad) ^ (r & 7)) * 8];
      }
#pragma unroll
      for (int i = 0; i < 2; i++)
#pragma unroll
        for (int j = 0; j < 4; j++)
          acc[i][j] = __builtin_amdgcn_mfma_f32_16x16x32_bf16(af[i], bfr[j], acc[i][j], 0, 0, 0);
    }
    __syncthreads();
  }
#pragma unroll
  for (int i = 0; i < 2; i++) {
    const int row = m0 + rw + i * 16 + quad * 4;
#pragma unroll
    for (int j = 0; j < 4; j++) {
      const int col = n0 + cw + j * 16 + qm;
#pragma unroll
      for (int r = 0; r < 4; r++)
        C[(size_t)(row + r) * 256 + col] = acc[i][j][r];
    }
  }
}

// ---------- MLP GEMM, tile 64x128, BK=64, fused bias+GELU+W2 dot -> atomic logits ----------
__global__ __launch_bounds__(256, 6) void gemm_gelu_w2(const u16* __restrict__ Axb,
                                                       const u16* __restrict__ Bt,
                                                       const float* __restrict__ b1,
                                                       const float* __restrict__ W2,
                                                       float* __restrict__ logits) {
  constexpr int K = 768;
  __shared__ u16 As[64 * 64];    // 8 KB
  __shared__ u16 Bs[128 * 64];   // 16 KB
  const int tid = threadIdx.x;
  const int n0 = blockIdx.x * 128;   // x = n for L2 sharing of A rows
  const int m0 = blockIdx.y * 64;
  const int wave = tid >> 6, lane = tid & 63, qm = lane & 15, quad = lane >> 4;
  const int rw = (wave >> 1) * 32, cw = (wave & 1) * 64;

  const int crow = tid >> 3;
  const int cpart = (tid & 7) ^ (crow & 7);
  const u16* Ap[2];
#pragma unroll
  for (int g = 0; g < 2; g++)
    Ap[g] = Axb + (size_t)(m0 + crow + g * 32) * K + cpart * 8;
  const u16* Bp[4];
#pragma unroll
  for (int g = 0; g < 4; g++)
    Bp[g] = Bt + (size_t)(n0 + crow + g * 32) * K + cpart * 8;

  f32x4 acc[2][4] = {};
  for (int kt = 0; kt < K; kt += 64) {
#pragma unroll
    for (int g = 0; g < 2; g++) gl_lds16(Ap[g] + kt, &As[(tid + g * 256) * 8]);
#pragma unroll
    for (int g = 0; g < 4; g++) gl_lds16(Bp[g] + kt, &Bs[(tid + g * 256) * 8]);
    __syncthreads();
#pragma unroll
    for (int s = 0; s < 2; s++) {
      short8 af[2], bfr[4];
#pragma unroll
      for (int i = 0; i < 2; i++) {
        const int r = rw + i * 16 + qm;
        af[i] = *(const short8*)&As[r * 64 + ((s * 4 + quad) ^ (r & 7)) * 8];
      }
#pragma unroll
      for (int j = 0; j < 4; j++) {
        const int r = cw + j * 16 + qm;
        bfr[j] = *(const short8*)&Bs[r * 64 + ((s * 4 + quad) ^ (r & 7)) * 8];
      }
#pragma unroll
      for (int i = 0; i < 2; i++)
#pragma unroll
        for (int j = 0; j < 4; j++)
          acc[i][j] = __builtin_amdgcn_mfma_f32_16x16x32_bf16(af[i], bfr[j], acc[i][j], 0, 0, 0);
    }
    __syncthreads();
  }

  // epilogue: partial logit = sum_j gelu(acc+b1)*W2; reduce over qm lanes; 1 atomic/row
  float w2j[4], bc[4];
#pragma unroll
  for (int j = 0; j < 4; j++) {
    const int col = n0 + cw + j * 16 + qm;
    w2j[j] = W2[col];
    bc[j] = b1[col];
  }
#pragma unroll
  for (int i = 0; i < 2; i++) {
#pragma unroll
    for (int r = 0; r < 4; r++) {
      float p = 0.0f;
#pragma unroll
      for (int j = 0; j < 4; j++)
        p += gelu_f(acc[i][j][r] + bc[j]) * w2j[j];
      p += __shfl_xor(p, 1);
      p += __shfl_xor(p, 2);
      p += __shfl_xor(p, 4);
      p += __shfl_xor(p, 8);
      if (qm == 0)
        atomicAdd(&logits[m0 + rw + i * 16 + quad * 4 + r], p);
    }
  }
}

// ---------- layernorm (bias added first) over both v and a ----------
__global__ __launch_bounds__(256) void ln2(float* __restrict__ v, float* __restrict__ a,
                                           const float* __restrict__ bv,
                                           const float* __restrict__ ba) {
  const int gr = blockIdx.x * 4 + (threadIdx.x >> 6);
  const int lane = threadIdx.x & 63;
  float* X; const float* bias; int row;
  if (gr < BT_ROWS) { X = v; bias = bv; row = gr; }
  else              { X = a; bias = ba; row = gr - BT_ROWS; }
  float4 x = *(float4*)&X[(size_t)row * 256 + lane * 4];
  const float4 b = *(const float4*)&bias[lane * 4];
  x.x += b.x; x.y += b.y; x.z += b.z; x.w += b.w;
  float s = x.x + x.y + x.z + x.w;
  float s2 = x.x * x.x + x.y * x.y + x.z * x.z + x.w * x.w;
  s = wave_bcast_sum(s);
  s2 = wave_bcast_sum(s2);
  const float mu = s * (1.0f / 256.0f);
  const float var = s2 * (1.0f / 256.0f) - mu * mu;
  const float inv = rsqrtf(var + 1e-5f);
  x.x = (x.x - mu) * inv; x.y = (x.y - mu) * inv;
  x.z = (x.z - mu) * inv; x.w = (x.w - mu) * inv;
  *(float4*)&X[(size_t)row * 256 + lane * 4] = x;
}

// ---------- fused: fractional shift + window avg + l2norm(actx,v) + concat ----------
__global__ __launch_bounds__(256) void shift_norm(const float* __restrict__ a,
                                                  const float* __restrict__ v,
                                                  float* __restrict__ actx,
                                                  u16* __restrict__ xb,
                                                  const float* __restrict__ theta) {
  const int row = blockIdx.x * 4 + (threadIdx.x >> 6);
  const int lane = threadIdx.x & 63;
  const int d4 = lane * 4;
  const int bb = row >> 11;
  const int t = row & (T_SEQ - 1);
  const float th = fminf(fmaxf(theta[0], -12.0f), 12.0f);
  const float delta = 2.0f + 4.0f * (1.0f / (1.0f + expf(-th)));
  const float dl = fminf(fmaxf(delta, 0.0f), (float)(T_SEQ - 1));
  const float nf = floorf(dl);
  const float alpha = dl - nf;
  const int ni = (int)nf;
  const float center = fminf(fmaxf((float)t + delta, 0.0f), (float)t);
  float sx = 0, sy = 0, sz = 0, sw = 0, cnt = 0.0f;
  const float* ab = a + (size_t)bb * T_SEQ * 256;
#pragma unroll
  for (int j = 0; j < 6; j++) {
    const int tau = t - 5 + j;
    if (tau < 0) continue;
    if (fabsf((float)tau - center) > 5.0f) continue;
    cnt += 1.0f;
    const int i0 = min(max(tau - ni, 0), T_SEQ - 1);
    const int i1 = min(i0 + 1, T_SEQ - 1);
    const float4 a0 = *(const float4*)&ab[(size_t)i0 * 256 + d4];
    const float4 a1 = *(const float4*)&ab[(size_t)i1 * 256 + d4];
    sx += a0.x + alpha * (a1.x - a0.x);
    sy += a0.y + alpha * (a1.y - a0.y);
    sz += a0.z + alpha * (a1.z - a0.z);
    sw += a0.w + alpha * (a1.w - a0.w);
  }
  const float sc = 1.0f / fmaxf(cnt, 1e-8f);
  float4 o; o.x = sx * sc; o.y = sy * sc; o.z = sz * sc; o.w = sw * sc;
  *(float4*)&actx[(size_t)row * 256 + d4] = o;
  const float4 vv = *(const float4*)&v[(size_t)row * 256 + d4];
  float sa2 = o.x * o.x + o.y * o.y + o.z * o.z + o.w * o.w;
  float sv2 = vv.x * vv.x + vv.y * vv.y + vv.z * vv.z + vv.w * vv.w;
  sa2 = wave_bcast_sum(sa2);
  sv2 = wave_bcast_sum(sv2);
  const float ia = 1.0f / fmaxf(sqrtf(sa2), 1e-8f);
  const float iv = 1.0f / fmaxf(sqrtf(sv2), 1e-8f);
  const float anx = o.x * ia, any_ = o.y * ia, anz = o.z * ia, anw = o.w * ia;
  const float vnx = vv.x * iv, vny = vv.y * iv, vnz = vv.z * iv, vnw = vv.w * iv;
  u16* xr = xb + (size_t)row * 768;
  u32 pa[2] = {pkbf(anx, any_), pkbf(anz, anw)};
  u32 pv[2] = {pkbf(vnx, vny), pkbf(vnz, vnw)};
  u32 pp[2] = {pkbf(anx * vnx, any_ * vny), pkbf(anz * vnz, anw * vnw)};
  *(uint2*)&xr[d4] = *(uint2*)pa;
  *(uint2*)&xr[256 + d4] = *(uint2*)pv;
  *(uint2*)&xr[512 + d4] = *(uint2*)pp;
}

// ---------- gate + mix ----------
__global__ __launch_bounds__(256) void gate_mix(const float* __restrict__ logits,
                                                const float* __restrict__ b2,
                                                const float* __restrict__ actx,
                                                const float* __restrict__ v,
                                                float* __restrict__ out) {
  const int row = blockIdx.x * 4 + (threadIdx.x >> 6);
  const int lane = threadIdx.x & 63;
  const float l = fminf(fmaxf(logits[row] + b2[0], -12.0f), 12.0f);
  float g = 1.0f / (1.0f + expf(-l));
  g = fminf(fmaxf(g, 0.05f), 0.95f);
  const float4 aa = *(const float4*)&actx[(size_t)row * 256 + lane * 4];
  const float4 vv = *(const float4*)&v[(size_t)row * 256 + lane * 4];
  float4 o;
  o.x = g * aa.x + (1.0f - g) * vv.x;
  o.y = g * aa.y + (1.0f - g) * vv.y;
  o.z = g * aa.z + (1.0f - g) * vv.z;
  o.w = g * aa.w + (1.0f - g) * vv.w;
  *(float4*)&out[(size_t)row * 256 + lane * 4] = o;
}

// ---------- launch ----------
extern "C" void kernel_launch(void* const* d_in, const int* in_sizes, int n_in,
                              void* d_out, int out_size, void* d_ws, size_t ws_size,
                              hipStream_t stream) {
  const float* video = (const float*)d_in[0];
  const float* audio = (const float*)d_in[1];
  const float* Wv    = (const float*)d_in[2];
  const float* bv    = (const float*)d_in[3];
  const float* Wa    = (const float*)d_in[4];
  const float* ba    = (const float*)d_in[5];
  const float* theta = (const float*)d_in[6];
  const float* W1    = (const float*)d_in[7];
  const float* b1    = (const float*)d_in[8];
  const float* W2    = (const float*)d_in[9];
  const float* b2    = (const float*)d_in[10];
  float* out = (float*)d_out;
  char* ws = (char*)d_ws;

  const size_t OFF_WVT = 0;          // [256][1024] bf16
  const size_t OFF_WAT = 524288;     // [256][768]  bf16
  const size_t OFF_W1T = 917504;     // [1024][768] bf16
  const size_t OFF_LOG = 2490368;    // [16384] f32
  const size_t OFF_V   = 2555904;    // [16384][256] f32
  const size_t OFF_A   = 19333120;   // [16384][256] f32
  const size_t OFF_ACTX= 36110336;   // [16384][256] f32
  const size_t OFF_XB  = 52887552;   // [16384][768] bf16

  u16* wvT = (u16*)(ws + OFF_WVT);
  u16* waT = (u16*)(ws + OFF_WAT);
  u16* w1T = (u16*)(ws + OFF_W1T);
  float* logits = (float*)(ws + OFF_LOG);
  float* v    = (float*)(ws + OFF_V);
  float* a    = (float*)(ws + OFF_A);
  float* actx = (float*)(ws + OFF_ACTX);
  u16* xb = (u16*)(ws + OFF_XB);

  tcvt_all<<<1216, 256, 0, stream>>>(Wv, Wa, W1, wvT, waT, w1T);
  hipMemsetAsync(logits, 0, BT_ROWS * sizeof(float), stream);
  gemm_proj<<<1024, 256, 0, stream>>>(video, audio, wvT, waT, v, a);
  ln2<<<2 * BT_ROWS / 4, 256, 0, stream>>>(v, a, bv, ba);
  shift_norm<<<BT_ROWS / 4, 256, 0, stream>>>(a, v, actx, xb, theta);
  gemm_gelu_w2<<<dim3(8, BT_ROWS / 64), 256, 0, stream>>>(xb, w1T, b1, W2, logits);
  gate_mix<<<BT_ROWS / 4, 256, 0, stream>>>(logits, b2, actx, v, out);
}